// Round 1
// baseline (1837.141 us; speedup 1.0000x reference)
//
#include <hip/hip_runtime.h>

// ---------------------------------------------------------------------------
// FlowMatchingShield: 50-step Euler sampler over a 5-layer MLP.
//   h = concat([state(254), x(2), temb(64)])  -> 320
//   h @ W0 split:  base = state@W0[0:254]+b0  (once)
//                  tvec[s] = temb(s)@W0[256:320] (once, 50 vectors)
//                  x-part = x@W0[254:256]  (elementwise per step)
//   per step: 3x (1024x1024x1024) GEMM+SiLU  [bf16 MFMA]
//             + head W4 (1024->2) + Euler update + next h0  [fp32 fused tail]
// ---------------------------------------------------------------------------

typedef __bf16 bf16x8 __attribute__((ext_vector_type(8)));
typedef float  f32x4  __attribute__((ext_vector_type(4)));
typedef unsigned short u16;
typedef u16 u16x8 __attribute__((ext_vector_type(8)));
typedef u16 u16x4 __attribute__((ext_vector_type(4)));

#define H 1024
#define BATCH 1024
#define SDIM 254
#define NSTEP 50
#define DT 0.02f
#define LDP 40  // padded LDS row stride (elements): 80 B, 16B-aligned, conflict-free

__device__ __forceinline__ u16 f2bf(float f) {
  unsigned int u = __float_as_uint(f);
  return (u16)((u + 0x7FFFu + ((u >> 16) & 1u)) >> 16);
}

__device__ __forceinline__ float silu(float v) {
  return v / (1.0f + __expf(-v));
}

// --- one-time: W[k][n] fp32 -> WT[n][k] bf16, for W1..W3 (blockIdx.z picks) --
__global__ void transpose_w(const float* __restrict__ A, const float* __restrict__ B,
                            const float* __restrict__ C, u16* __restrict__ TA,
                            u16* __restrict__ TB, u16* __restrict__ TC) {
  const float* W = (blockIdx.z == 0) ? A : (blockIdx.z == 1) ? B : C;
  u16* T = (blockIdx.z == 0) ? TA : (blockIdx.z == 1) ? TB : TC;
  __shared__ float tile[32][33];
  const int n0 = blockIdx.x * 32, k0 = blockIdx.y * 32;
  const int tx = threadIdx.x & 31, ty = threadIdx.x >> 5;  // 32 x 8
#pragma unroll
  for (int i = 0; i < 4; ++i)
    tile[ty + 8 * i][tx] = W[(k0 + ty + 8 * i) * H + n0 + tx];
  __syncthreads();
#pragma unroll
  for (int i = 0; i < 4; ++i)
    T[(size_t)(n0 + ty + 8 * i) * H + k0 + tx] = f2bf(tile[tx][ty + 8 * i]);
}

// --- one-time: base[b][n] = b0[n] + sum_k state[b][k]*W0[k][n] (k<254) -------
__global__ void base_gemm(const float* __restrict__ state, const float* __restrict__ W0,
                          const float* __restrict__ b0, float* __restrict__ base) {
  __shared__ float srow[SDIM];
  const int b = blockIdx.x, tid = threadIdx.x;
  if (tid < SDIM) srow[tid] = state[b * SDIM + tid];
  __syncthreads();
  const int n = tid * 4;
  float4 bv = *(const float4*)&b0[n];
  float a0 = bv.x, a1 = bv.y, a2 = bv.z, a3 = bv.w;
  for (int k = 0; k < SDIM; ++k) {
    float s = srow[k];
    float4 w = *(const float4*)&W0[k * H + n];
    a0 += s * w.x; a1 += s * w.y; a2 += s * w.z; a3 += s * w.w;
  }
  float4 r = {a0, a1, a2, a3};
  *(float4*)&base[(size_t)b * H + n] = r;
}

// --- one-time: tvec[s][h] = sum_j sin(t fj) W0[256+j][h] + cos(t fj) W0[288+j][h]
__global__ void tvec_kernel(const float* __restrict__ W0, float* __restrict__ tvec) {
  const int s = blockIdx.x;
  const int h = blockIdx.y * 256 + threadIdx.x;
  const float t = (float)s * DT;
  float acc = 0.0f;
#pragma unroll
  for (int j = 0; j < 32; ++j) {
    float fr = __expf((float)j * (-9.210340371976184f / 31.0f));
    float ang = t * fr;
    acc += __sinf(ang) * W0[(256 + j) * H + h] + __cosf(ang) * W0[(288 + j) * H + h];
  }
  tvec[s * H + h] = acc;
}

// --- one-time: h0 for step 0 (bf16) + seed x into d_out ----------------------
__global__ void init_kernel(const float* __restrict__ base, const float* __restrict__ tvec,
                            const float* __restrict__ x0, const float* __restrict__ W0,
                            u16* __restrict__ h0, float* __restrict__ xout) {
  const int b = blockIdx.x, tid = threadIdx.x;
  const float xa = x0[2 * b], xb = x0[2 * b + 1];
  if (tid == 0) { xout[2 * b] = xa; xout[2 * b + 1] = xb; }
  const int n = tid * 4;
  float4 bs = *(const float4*)&base[(size_t)b * H + n];
  float4 tv = *(const float4*)&tvec[n];
  float4 wa = *(const float4*)&W0[254 * H + n];
  float4 wb = *(const float4*)&W0[255 * H + n];
  u16x4 r;
  r[0] = f2bf(silu(bs.x + tv.x + xa * wa.x + xb * wb.x));
  r[1] = f2bf(silu(bs.y + tv.y + xa * wa.y + xb * wb.y));
  r[2] = f2bf(silu(bs.z + tv.z + xa * wa.z + xb * wb.z));
  r[3] = f2bf(silu(bs.w + tv.w + xa * wa.w + xb * wb.w));
  *(u16x4*)&h0[(size_t)b * H + n] = r;
}

// --- main GEMM: out = silu(A @ WT^T + bias); A bf16 [1024x1024], WT bf16 [N][K]
// single-wave blocks (64 thr), 32x32 tile, BK=32, register prefetch, no barrier
__global__ __launch_bounds__(64) void gemm_mfma(const u16* __restrict__ A,
                                                const u16* __restrict__ BT,
                                                const float* __restrict__ bias,
                                                void* __restrict__ out, int out_bf16) {
  __shared__ u16 As[32 * LDP];
  __shared__ u16 Bs[32 * LDP];
  const int tid = threadIdx.x;
  const int bn = blockIdx.x, bm = blockIdx.y;
  const int lr = tid & 15, quad = tid >> 4;

  const int srow = tid >> 2;       // 0..15 (two rows: srow, srow+16)
  const int skc = (tid & 3) * 8;   // 0,8,16,24

  const u16* Ap = A + (size_t)(bm * 32 + srow) * H + skc;
  const u16* Bp = BT + (size_t)(bn * 32 + srow) * H + skc;

  f32x4 acc[2][2] = {};

  u16x8 ga0 = *(const u16x8*)(Ap);
  u16x8 ga1 = *(const u16x8*)(Ap + 16 * H);
  u16x8 gb0 = *(const u16x8*)(Bp);
  u16x8 gb1 = *(const u16x8*)(Bp + 16 * H);

  for (int kt = 0; kt < 32; ++kt) {
    *(u16x8*)&As[srow * LDP + skc] = ga0;
    *(u16x8*)&As[(srow + 16) * LDP + skc] = ga1;
    *(u16x8*)&Bs[srow * LDP + skc] = gb0;
    *(u16x8*)&Bs[(srow + 16) * LDP + skc] = gb1;
    if (kt < 31) {  // prefetch next K-tile into registers
      const int off = (kt + 1) * 32;
      ga0 = *(const u16x8*)(Ap + off);
      ga1 = *(const u16x8*)(Ap + 16 * H + off);
      gb0 = *(const u16x8*)(Bp + off);
      gb1 = *(const u16x8*)(Bp + 16 * H + off);
    }
    // fragment loads (in-wave DS ordering makes this safe without a barrier)
    bf16x8 a0 = *(const bf16x8*)&As[lr * LDP + quad * 8];
    bf16x8 a1 = *(const bf16x8*)&As[(16 + lr) * LDP + quad * 8];
    bf16x8 b0 = *(const bf16x8*)&Bs[lr * LDP + quad * 8];
    bf16x8 b1 = *(const bf16x8*)&Bs[(16 + lr) * LDP + quad * 8];
    acc[0][0] = __builtin_amdgcn_mfma_f32_16x16x32_bf16(a0, b0, acc[0][0], 0, 0, 0);
    acc[0][1] = __builtin_amdgcn_mfma_f32_16x16x32_bf16(a0, b1, acc[0][1], 0, 0, 0);
    acc[1][0] = __builtin_amdgcn_mfma_f32_16x16x32_bf16(a1, b0, acc[1][0], 0, 0, 0);
    acc[1][1] = __builtin_amdgcn_mfma_f32_16x16x32_bf16(a1, b1, acc[1][1], 0, 0, 0);
  }

#pragma unroll
  for (int mt = 0; mt < 2; ++mt)
#pragma unroll
    for (int nt = 0; nt < 2; ++nt) {
      const int gm = bm * 32 + mt * 16 + quad * 4;
      const int gn = bn * 32 + nt * 16 + lr;
      const float bv = bias[gn];
      f32x4 v = acc[mt][nt];
#pragma unroll
      for (int r = 0; r < 4; ++r) {
        float x = silu(v[r] + bv);  // all three hidden layers have SiLU
        if (out_bf16) ((u16*)out)[(size_t)(gm + r) * H + gn] = f2bf(x);
        else          ((float*)out)[(size_t)(gm + r) * H + gn] = x;
      }
    }
}

// --- per-step tail: v = h3@W4+b4 ; x += dt*v ; h0(next) = silu(base+tvec+x.W0x)
__global__ void tail_kernel(const float* __restrict__ h3, const float* __restrict__ W4,
                            const float* __restrict__ b4, float* __restrict__ x,
                            const float* __restrict__ base, const float* __restrict__ tvec,
                            const float* __restrict__ W0, u16* __restrict__ h0, int s) {
  const int b = blockIdx.x, tid = threadIdx.x;
  float s0 = 0.0f, s1 = 0.0f;
  for (int h = tid; h < H; h += 256) {
    float v = h3[(size_t)b * H + h];
    s0 += v * W4[2 * h];
    s1 += v * W4[2 * h + 1];
  }
#pragma unroll
  for (int o = 32; o > 0; o >>= 1) {
    s0 += __shfl_down(s0, o);
    s1 += __shfl_down(s1, o);
  }
  __shared__ float red[8];
  __shared__ float xs[2];
  const int w = tid >> 6;
  if ((tid & 63) == 0) { red[w * 2] = s0; red[w * 2 + 1] = s1; }
  __syncthreads();
  if (tid == 0) {
    float v0 = red[0] + red[2] + red[4] + red[6] + b4[0];
    float v1 = red[1] + red[3] + red[5] + red[7] + b4[1];
    float xa = x[2 * b] + DT * v0;
    float xb = x[2 * b + 1] + DT * v1;
    x[2 * b] = xa; x[2 * b + 1] = xb;
    xs[0] = xa; xs[1] = xb;
  }
  __syncthreads();
  if (s < NSTEP - 1) {
    const float xa = xs[0], xb = xs[1];
    const int n = tid * 4;
    float4 bs = *(const float4*)&base[(size_t)b * H + n];
    float4 tv = *(const float4*)&tvec[(size_t)(s + 1) * H + n];
    float4 wa = *(const float4*)&W0[254 * H + n];
    float4 wb = *(const float4*)&W0[255 * H + n];
    u16x4 r;
    r[0] = f2bf(silu(bs.x + tv.x + xa * wa.x + xb * wb.x));
    r[1] = f2bf(silu(bs.y + tv.y + xa * wa.y + xb * wb.y));
    r[2] = f2bf(silu(bs.z + tv.z + xa * wa.z + xb * wb.z));
    r[3] = f2bf(silu(bs.w + tv.w + xa * wa.w + xb * wb.w));
    *(u16x4*)&h0[(size_t)b * H + n] = r;
  }
}

extern "C" void kernel_launch(void* const* d_in, const int* in_sizes, int n_in,
                              void* d_out, int out_size, void* d_ws, size_t ws_size,
                              hipStream_t stream) {
  const float* state = (const float*)d_in[0];
  const float* x0    = (const float*)d_in[1];
  const float* W0    = (const float*)d_in[2];
  const float* b0    = (const float*)d_in[3];
  const float* W1    = (const float*)d_in[4];
  const float* b1    = (const float*)d_in[5];
  const float* W2    = (const float*)d_in[6];
  const float* b2    = (const float*)d_in[7];
  const float* W3    = (const float*)d_in[8];
  const float* b3    = (const float*)d_in[9];
  const float* W4    = (const float*)d_in[10];
  const float* b4    = (const float*)d_in[11];
  float* xout = (float*)d_out;

  char* ws = (char*)d_ws;
  const size_t MB = 1024 * 1024;
  float* base = (float*)(ws + 0);          // 4 MiB
  float* h3f  = (float*)(ws + 4 * MB);     // 4 MiB
  float* tvec = (float*)(ws + 8 * MB);     // 200 KiB (reserve 256 KiB)
  u16* w1t = (u16*)(ws + 8 * MB + 256 * 1024);               // 2 MiB each
  u16* w2t = (u16*)(ws + 10 * MB + 256 * 1024);
  u16* w3t = (u16*)(ws + 12 * MB + 256 * 1024);
  u16* hA  = (u16*)(ws + 14 * MB + 256 * 1024);
  u16* hB  = (u16*)(ws + 16 * MB + 256 * 1024);
  u16* hC  = (u16*)(ws + 18 * MB + 256 * 1024);

  transpose_w<<<dim3(32, 32, 3), 256, 0, stream>>>(W1, W2, W3, w1t, w2t, w3t);
  base_gemm<<<BATCH, 256, 0, stream>>>(state, W0, b0, base);
  tvec_kernel<<<dim3(NSTEP, 4), 256, 0, stream>>>(W0, tvec);
  init_kernel<<<BATCH, 256, 0, stream>>>(base, tvec, x0, W0, hA, xout);

  for (int s = 0; s < NSTEP; ++s) {
    gemm_mfma<<<dim3(32, 32), 64, 0, stream>>>(hA, w1t, b1, hB, 1);
    gemm_mfma<<<dim3(32, 32), 64, 0, stream>>>(hB, w2t, b2, hC, 1);
    gemm_mfma<<<dim3(32, 32), 64, 0, stream>>>(hC, w3t, b3, h3f, 0);
    tail_kernel<<<BATCH, 256, 0, stream>>>(h3f, W4, b4, xout, base, tvec, W0, hA, s);
  }
}